// Round 18
// baseline (70.581 us; speedup 1.0000x reference)
//
#include <hip/hip_runtime.h>

typedef unsigned long long u64;

#define IMG 1024
#define RH  32                 // output rows per wave-band
#define NBANDS (IMG / RH)      // 32
#define OUTW 48                // output cols per wave (64 - 2*8 margin)
#define NSTRIP 22              // ceil(1024/48)
#define NEG_INF (-__builtin_inff())

// ---- DPP lane+-1 exchange; bound_ctrl -> 0.0 at wave edges.
// 0.0 edges NEVER alter any max/equality here: every window contains its center,
// all real values are >= 0, so max >= 0 and an extra 0.0 candidate is absorbed.
__device__ __forceinline__ float dpp_shr1_f(float x) {
    return __uint_as_float((unsigned)__builtin_amdgcn_update_dpp(0, (int)__float_as_uint(x), 0x138, 0xf, 0xf, true));
}
__device__ __forceinline__ float dpp_shl1_f(float x) {
    return __uint_as_float((unsigned)__builtin_amdgcn_update_dpp(0, (int)__float_as_uint(x), 0x130, 0xf, 0xf, true));
}

__device__ __forceinline__ float max3f(float a, float b, float c) { return fmaxf(fmaxf(a, b), c); }

// per-lane bit of a wave-uniform u64 plane (compiles to cndmask w/ sgpr-pair mask)
__device__ __forceinline__ bool lane_bit(u64 m, int lane) {
#if __has_builtin(__builtin_amdgcn_inverse_ballot_w64)
    (void)lane;
    return __builtin_amdgcn_inverse_ballot_w64(m);
#else
    return ((m >> (unsigned)lane) & 1ull) != 0ull;
#endif
}

// d = mask_bit ? 0 : v
__device__ __forceinline__ float cnd_zero(float v, u64 m, int lane) {
    return lane_bit(m, lane) ? 0.f : v;
}
// d = mask_bit ? v : 0
__device__ __forceinline__ float cnd_keep(float v, u64 m, int lane) {
    return lane_bit(m, lane) ? v : 0.f;
}

// horizontal 3-OR dilation on a wave-wide bit plane (uniform u64 -> SALU)
__device__ __forceinline__ u64 hor3s(u64 m) { return m | (m << 1) | (m >> 1); }

#define RV(r) (((unsigned)(r) < (unsigned)lmax) ? ~0ull : 0ull)

// One pipeline step at row s = sb+K (K compile-time).
// H[i] <-> scores row sb-10+i. Planes: M0[i]<->m0 row sb+i-6, HM0/S1A/SS1 idx i<->row sb+i-6
// (HM0 shifted: HM0[K+2]<->hm0 s-3), MK1/S2A/SS2 idx i<->row sb+i-10, H1[i]<->row sb+i-7, H2[i]<->row sb+i-11.
#define STEP(K) do {                                                                     \
    const int s_ = sb + (K);                                                             \
    const u64 rv2 = RV(s_-2), rv4 = RV(s_-4), rv6 = RV(s_-6), rv8 = RV(s_-8), rv10 = RV(s_-10); \
    /* hmax(scores) row s-1 */                                                           \
    HV[(K)+2] = max3f(dpp_shr1_f(H[9+(K)]), H[9+(K)], dpp_shl1_f(H[9+(K)]));             \
    /* m0 row s-2 */                                                                     \
    float vm0 = max3f(HV[(K)+2], HV[(K)+1], HV[(K)]);                                    \
    M0[(K)+4] = __ballot(H[8+(K)] == vm0) & rv2 & cvm;                                   \
    /* hm0 row s-3 */                                                                    \
    HM0[(K)+2] = hor3s(M0[(K)+3]);                                                       \
    /* supp1 row s-4 */                                                                  \
    S1A[(K)+2] = HM0[(K)+2] | HM0[(K)+1] | HM0[(K)];                                     \
    /* ss1 row s-4 */                                                                    \
    SS1[(K)+2] = cnd_zero(H[6+(K)], S1A[(K)+2] & rv4, lane);                             \
    /* hmax(ss1) row s-5 */                                                              \
    H1[(K)+2] = max3f(dpp_shr1_f(SS1[(K)+1]), SS1[(K)+1], dpp_shl1_f(SS1[(K)+1]));       \
    /* mask1 row s-6 */                                                                  \
    float vm1 = max3f(H1[(K)+2], H1[(K)+1], H1[(K)]);                                    \
    u64 nm1 = __ballot(SS1[(K)] == vm1) & rv6 & cvm;                                     \
    MK1[(K)+4] = M0[(K)] | (nm1 & ~S1A[(K)]);                                            \
    /* hm1 row s-7 */                                                                    \
    HM1[(K)+2] = hor3s(MK1[(K)+3]);                                                      \
    /* supp2 row s-8 */                                                                  \
    S2A[(K)+2] = HM1[(K)+2] | HM1[(K)+1] | HM1[(K)];                                     \
    /* ss2 row s-8 */                                                                    \
    SS2[(K)+2] = cnd_zero(H[2+(K)], S2A[(K)+2] & rv8, lane);                             \
    /* hmax(ss2) row s-9 */                                                              \
    H2[(K)+2] = max3f(dpp_shr1_f(SS2[(K)+1]), SS2[(K)+1], dpp_shl1_f(SS2[(K)+1]));       \
    /* mask2 + output row s-10 */                                                        \
    float vm2 = max3f(H2[(K)+2], H2[(K)+1], H2[(K)]);                                    \
    u64 nm2 = __ballot(SS2[(K)] == vm2) & rv10 & cvm;                                    \
    u64 mk2 = MK1[(K)] | (nm2 & ~S2A[(K)]);                                              \
    const int srow = s_ - 10;                                                            \
    if (srow >= y0 && srow < yend) {     /* uniform branch */                            \
        float ov = cnd_keep(H[(K)], mk2, lane);                                          \
        if (out_ok) opl[(size_t)srow * IMG] = ov;                                        \
    }                                                                                    \
} while (0)

__global__ __launch_bounds__(256, 2)
void nms_sweep(const float* __restrict__ in, float* __restrict__ out)
{
    const int tid  = threadIdx.x;
    const int lane = tid & 63;
    const int w    = tid >> 6;

    // wave task: wid -> (strip, band); consecutive wid = adjacent bands (vertical L2 reuse)
    const int wid   = (int)blockIdx.x * 4 + w;            // 0 .. NSTRIP*NBANDS-1
    const int strip = wid / NBANDS;
    const int band  = wid - strip * NBANDS;
    const int y0    = band * RH;
    const int yend  = y0 + RH;
    const size_t base = (size_t)blockIdx.y * ((size_t)IMG * IMG);
    const int lmax  = (yend + 5 < IMG) ? yend + 5 : IMG;

    // one column per lane; input col may be OOB (margin/tails)
    const int col     = strip * OUTW - 8 + lane;
    const bool col_ok = (unsigned)col < (unsigned)IMG;
    const bool out_ok = (lane >= 8) && (lane < 8 + OUTW) && (col < IMG);
    const u64  cvm    = __ballot(col_ok);                 // valid-column bit plane

    const float* ipl = in  + base + col;                  // dereferenced only when col_ok
    float*       opl = out + base + col;

    float H[14], Hn[4], HV[6], SS1[6], H1[6], SS2[6], H2[6];
#pragma unroll
    for (int i = 0; i < 14; ++i) H[i] = NEG_INF;
#pragma unroll
    for (int i = 0; i < 6; ++i) { HV[i]=NEG_INF; SS1[i]=NEG_INF; H1[i]=NEG_INF; SS2[i]=NEG_INF; H2[i]=NEG_INF; }
    u64 M0[8], HM0[6], S1A[6], MK1[8], HM1[6], S2A[6];
#pragma unroll
    for (int i = 0; i < 8; ++i) { M0[i] = 0; MK1[i] = 0; }
#pragma unroll
    for (int i = 0; i < 6; ++i) { HM0[i] = 0; S1A[i] = 0; HM1[i] = 0; S2A[i] = 0; }

    int sb = y0 - 5;

    // prologue: group 0 rows
#pragma unroll
    for (int k = 0; k < 4; ++k) {
        const int r = sb + k;
        H[10 + k] = (col_ok && (unsigned)r < (unsigned)lmax) ? ipl[(size_t)r * IMG] : NEG_INF;
    }

#pragma unroll 1
    for (int it = 0; it < (RH + 15 + 3) / 4; ++it) {
        // prefetch next group's rows (no barriers anywhere; loads stay in flight)
#pragma unroll
        for (int k = 0; k < 4; ++k) {
            const int r = sb + 4 + k;
            Hn[k] = (col_ok && (unsigned)r < (unsigned)lmax) ? ipl[(size_t)r * IMG] : NEG_INF;
        }

        STEP(0);
        STEP(1);
        STEP(2);
        STEP(3);

        // rotate by 4 rows (all static indices; planes rotate on SALU)
#pragma unroll
        for (int i = 0; i < 10; ++i) H[i] = H[i + 4];
        H[10] = Hn[0]; H[11] = Hn[1]; H[12] = Hn[2]; H[13] = Hn[3];
        HV[0]=HV[4];   HV[1]=HV[5];
        SS1[0]=SS1[4]; SS1[1]=SS1[5];
        H1[0]=H1[4];   H1[1]=H1[5];
        SS2[0]=SS2[4]; SS2[1]=SS2[5];
        H2[0]=H2[4];   H2[1]=H2[5];
        M0[0]=M0[4];   M0[1]=M0[5];   M0[2]=M0[6];   M0[3]=M0[7];
        MK1[0]=MK1[4]; MK1[1]=MK1[5]; MK1[2]=MK1[6]; MK1[3]=MK1[7];
        HM0[0]=HM0[4]; HM0[1]=HM0[5];
        S1A[0]=S1A[4]; S1A[1]=S1A[5];
        HM1[0]=HM1[4]; HM1[1]=HM1[5];
        S2A[0]=S2A[4]; S2A[1]=S2A[5];
        sb += 4;
    }
}

extern "C" void kernel_launch(void* const* d_in, const int* in_sizes, int n_in,
                              void* d_out, int out_size, void* d_ws, size_t ws_size,
                              hipStream_t stream) {
    const float* in = (const float*)d_in[0];
    float* out = (float*)d_out;
    const int batch = in_sizes[0] / (IMG * IMG);
    dim3 grid((NSTRIP * NBANDS) / 4, batch, 1);   // 4 independent waves per block
    nms_sweep<<<grid, dim3(256, 1, 1), 0, stream>>>(in, out);
}